// Round 6
// 162.881 us; speedup vs baseline: 1.0939x; 1.0939x over previous
//
#include <hip/hip_runtime.h>

#define NBLK 256

// tanh(x) = 1 - 2/(exp2(x*2*log2e)+1); v_exp_f32 is native exp2 -> saves the ln2 mul.
// abs err ~3e-7, well inside the 1.69e-3 budget (baseline-proven numerics class).
__device__ __forceinline__ float fast_tanh(float x) {
    float e = __builtin_amdgcn_exp2f(x * 2.88539008f);   // exp(2x)
    return 1.0f - 2.0f * __builtin_amdgcn_rcpf(e + 1.0f);
}

__global__ __launch_bounds__(NBLK) void pinn_kernel(
    const float* __restrict__ T,
    const float* __restrict__ W1, const float* __restrict__ b1,
    const float* __restrict__ W2, const float* __restrict__ b2,
    const float* __restrict__ W3, const float* __restrict__ b3,
    const float* __restrict__ W4, const float* __restrict__ b4,
    const float* __restrict__ Wo, const float* __restrict__ bo,
    const float* __restrict__ C1, const float* __restrict__ C2, const float* __restrict__ C3,
    float* __restrict__ out, int n)
{
    // No LDS. No early-exit (keeps control flow uniform so uniform weight loads
    // scalarize to s_load on the SMEM pipe instead of hammering LDS/VMEM).
    const int i0 = blockIdx.x * NBLK + threadIdx.x;
    const int i  = (i0 < n) ? i0 : (n - 1);        // clamp loads; store guarded below
    const float t = T[i];

    float h[20], d[20];

    // ---- layer 1: z = t*W1 + b1, tangent dz = W1 (dt = 1) ----
#pragma unroll
    for (int j = 0; j < 20; ++j) {
        const float w = W1[j];
        const float e = fast_tanh(fmaf(t, w, b1[j]));
        h[j] = e;
        d[j] = (1.0f - e * e) * w;
    }

    // ---- layers 2..4: k-outer / j-inner. Row W[k][0..19] is contiguous ->
    // SMEM load-widening merges into s_load_dwordx16/x4. h/d updated in place
    // after the k-loop (no nh/ndh copy registers). L rolled for i-cache.
#pragma unroll 1
    for (int L = 0; L < 3; ++L) {
        const float* __restrict__ WP = (L == 0) ? W2 : (L == 1) ? W3 : W4;
        const float* __restrict__ BP = (L == 0) ? b2 : (L == 1) ? b3 : b4;
        float a[20], dd[20];
#pragma unroll
        for (int j = 0; j < 20; ++j) { a[j] = BP[j]; dd[j] = 0.0f; }
#pragma unroll
        for (int k = 0; k < 20; ++k) {
            const float hk = h[k], dk = d[k];
#pragma unroll
            for (int j = 0; j < 20; ++j) {
                const float w = WP[k * 20 + j];   // uniform addr -> scalar load
                a[j]  = fmaf(hk, w, a[j]);
                dd[j] = fmaf(dk, w, dd[j]);
            }
        }
#pragma unroll
        for (int j = 0; j < 20; ++j) {
            const float e = fast_tanh(a[j]);
            h[j] = e;
            d[j] = (1.0f - e * e) * dd[j];
        }
    }

    // ---- output layer: o = h@Wo + bo, go = d@Wo ----
    float o0 = bo[0], o1 = bo[1], o2 = bo[2];
    float g0 = 0.0f, g1 = 0.0f, g2 = 0.0f;
#pragma unroll
    for (int k = 0; k < 20; ++k) {
        const float hk = h[k], dk = d[k];
        const float w0 = Wo[k * 3 + 0];
        const float w1 = Wo[k * 3 + 1];
        const float w2 = Wo[k * 3 + 2];
        o0 = fmaf(hk, w0, o0);  g0 = fmaf(dk, w0, g0);
        o1 = fmaf(hk, w1, o1);  g1 = fmaf(dk, w1, g1);
        o2 = fmaf(hk, w2, o2);  g2 = fmaf(dk, w2, g2);
    }

    const float x = o0, y = o1, zz = o2;
    const float c1 = C1[0], c2 = C2[0], c3 = C3[0];
    const float fx = g0 - c1 * (y - x);
    const float fy = g1 - x * (c2 - zz) + y;
    const float fz = g2 - x * y + c3 * zz;

    if (i0 < n) {
        // 24*i bytes is 8B-aligned -> three float2 stores
        float2* po = reinterpret_cast<float2*>(out + (size_t)i0 * 6);
        po[0] = make_float2(x,  y);
        po[1] = make_float2(zz, fx);
        po[2] = make_float2(fy, fz);
    }
}

extern "C" void kernel_launch(void* const* d_in, const int* in_sizes, int n_in,
                              void* d_out, int out_size, void* d_ws, size_t ws_size,
                              hipStream_t stream) {
    const float* T  = (const float*)d_in[0];
    const float* W1 = (const float*)d_in[1];
    const float* b1 = (const float*)d_in[2];
    const float* W2 = (const float*)d_in[3];
    const float* b2 = (const float*)d_in[4];
    const float* W3 = (const float*)d_in[5];
    const float* b3 = (const float*)d_in[6];
    const float* W4 = (const float*)d_in[7];
    const float* b4 = (const float*)d_in[8];
    const float* Wo = (const float*)d_in[9];
    const float* bo = (const float*)d_in[10];
    const float* C1 = (const float*)d_in[11];
    const float* C2 = (const float*)d_in[12];
    const float* C3 = (const float*)d_in[13];
    float* out = (float*)d_out;

    const int n = in_sizes[0];
    const int blocks = (n + NBLK - 1) / NBLK;
    pinn_kernel<<<blocks, NBLK, 0, stream>>>(T, W1, b1, W2, b2, W3, b3, W4, b4,
                                             Wo, bo, C1, C2, C3, out, n);
}

// Round 7
// 145.713 us; speedup vs baseline: 1.2228x; 1.1178x over previous
//
#include <hip/hip_runtime.h>

#define NBLK 256

typedef float f2 __attribute__((ext_vector_type(2)));   // VGPR pair -> v_pk_* f32 ops

// tanh(x) = 1 - 2/(exp2(2*log2e*x)+1); v_exp_f32 is native exp2. abs err ~3e-7.
__device__ __forceinline__ float fast_tanh(float x) {
    float e = __builtin_amdgcn_exp2f(x * 2.88539008f);   // exp(2x)
    return 1.0f - 2.0f * __builtin_amdgcn_rcpf(e + 1.0f);
}

#if __has_builtin(__builtin_elementwise_fma)
__device__ __forceinline__ f2 pk_fma(f2 a, f2 b, f2 c) { return __builtin_elementwise_fma(a, b, c); }
#else
__device__ __forceinline__ f2 pk_fma(f2 a, f2 b, f2 c) {
    f2 r; r.x = fmaf(a.x, b.x, c.x); r.y = fmaf(a.y, b.y, c.y); return r;
}
#endif

__global__ __launch_bounds__(NBLK) void pinn_kernel(
    const float* __restrict__ T,
    const float* __restrict__ W1, const float* __restrict__ b1,
    const float* __restrict__ W2, const float* __restrict__ b2,
    const float* __restrict__ W3, const float* __restrict__ b3,
    const float* __restrict__ W4, const float* __restrict__ b4,
    const float* __restrict__ Wo, const float* __restrict__ bo,
    const float* __restrict__ C1, const float* __restrict__ C2, const float* __restrict__ C3,
    float* __restrict__ out, int n)
{
    // No LDS; uniform control flow so all weight reads stay scalar (s_load, SMEM pipe).
    const int i0 = blockIdx.x * NBLK + threadIdx.x;
    const int i  = (i0 < n) ? i0 : (n - 1);        // clamp loads; store guarded below
    const float t = T[i];

    // State held as j-pairs: H[jj] = (h[2jj], h[2jj+1]), Dv likewise.
    f2 H[10], Dv[10];

    // ---- layer 1: z = t*W1 + b1, tangent dz = W1 (dt = 1) ----
#pragma unroll
    for (int jj = 0; jj < 10; ++jj) {
        const f2 w = *reinterpret_cast<const f2*>(W1 + 2 * jj);   // uniform -> s_load x2
        const f2 b = *reinterpret_cast<const f2*>(b1 + 2 * jj);
        f2 e;
        e.x = fast_tanh(fmaf(t, w.x, b.x));
        e.y = fast_tanh(fmaf(t, w.y, b.y));
        H[jj] = e;
        Dv[jj] = (1.0f - e * e) * w;               // packed mul/sub/mul
    }

    // ---- layers 2..4: k-outer / jj-inner, all FMA as v_pk_fma_f32.
    // Weight pair (W[k][2jj], W[k][2jj+1]) is a contiguous 8B uniform load.
#pragma unroll 1
    for (int L = 0; L < 3; ++L) {
        const float* __restrict__ WP = (L == 0) ? W2 : (L == 1) ? W3 : W4;
        const float* __restrict__ BP = (L == 0) ? b2 : (L == 1) ? b3 : b4;
        f2 A[10], DD[10];
#pragma unroll
        for (int jj = 0; jj < 10; ++jj) {
            A[jj]  = *reinterpret_cast<const f2*>(BP + 2 * jj);
            DD[jj] = (f2){0.0f, 0.0f};
        }
#pragma unroll
        for (int k = 0; k < 20; ++k) {
            const float hk = (k & 1) ? H[k >> 1].y  : H[k >> 1].x;   // static extract
            const float dk = (k & 1) ? Dv[k >> 1].y : Dv[k >> 1].x;
            const f2 hk2 = {hk, hk};
            const f2 dk2 = {dk, dk};
#pragma unroll
            for (int jj = 0; jj < 10; ++jj) {
                const f2 w2 = *reinterpret_cast<const f2*>(WP + k * 20 + 2 * jj);
                A[jj]  = pk_fma(hk2, w2, A[jj]);
                DD[jj] = pk_fma(dk2, w2, DD[jj]);
            }
        }
#pragma unroll
        for (int jj = 0; jj < 10; ++jj) {
            f2 e;
            e.x = fast_tanh(A[jj].x);
            e.y = fast_tanh(A[jj].y);
            H[jj] = e;
            Dv[jj] = (1.0f - e * e) * DD[jj];      // packed
        }
    }

    // ---- output layer: o = h@Wo + bo, go = d@Wo (scalar; 120 FMA) ----
    float o0 = bo[0], o1 = bo[1], o2 = bo[2];
    float g0 = 0.0f, g1 = 0.0f, g2 = 0.0f;
#pragma unroll
    for (int k = 0; k < 20; ++k) {
        const float hk = (k & 1) ? H[k >> 1].y  : H[k >> 1].x;
        const float dk = (k & 1) ? Dv[k >> 1].y : Dv[k >> 1].x;
        const float w0 = Wo[k * 3 + 0];
        const float w1 = Wo[k * 3 + 1];
        const float w2 = Wo[k * 3 + 2];
        o0 = fmaf(hk, w0, o0);  g0 = fmaf(dk, w0, g0);
        o1 = fmaf(hk, w1, o1);  g1 = fmaf(dk, w1, g1);
        o2 = fmaf(hk, w2, o2);  g2 = fmaf(dk, w2, g2);
    }

    const float x = o0, y = o1, zz = o2;
    const float c1 = C1[0], c2 = C2[0], c3 = C3[0];
    const float fx = g0 - c1 * (y - x);
    const float fy = g1 - x * (c2 - zz) + y;
    const float fz = g2 - x * y + c3 * zz;

    if (i0 < n) {
        // 24*i bytes is 8B-aligned -> three float2 stores
        float2* po = reinterpret_cast<float2*>(out + (size_t)i0 * 6);
        po[0] = make_float2(x,  y);
        po[1] = make_float2(zz, fx);
        po[2] = make_float2(fy, fz);
    }
}

extern "C" void kernel_launch(void* const* d_in, const int* in_sizes, int n_in,
                              void* d_out, int out_size, void* d_ws, size_t ws_size,
                              hipStream_t stream) {
    const float* T  = (const float*)d_in[0];
    const float* W1 = (const float*)d_in[1];
    const float* b1 = (const float*)d_in[2];
    const float* W2 = (const float*)d_in[3];
    const float* b2 = (const float*)d_in[4];
    const float* W3 = (const float*)d_in[5];
    const float* b3 = (const float*)d_in[6];
    const float* W4 = (const float*)d_in[7];
    const float* b4 = (const float*)d_in[8];
    const float* Wo = (const float*)d_in[9];
    const float* bo = (const float*)d_in[10];
    const float* C1 = (const float*)d_in[11];
    const float* C2 = (const float*)d_in[12];
    const float* C3 = (const float*)d_in[13];
    float* out = (float*)d_out;

    const int n = in_sizes[0];
    const int blocks = (n + NBLK - 1) / NBLK;
    pinn_kernel<<<blocks, NBLK, 0, stream>>>(T, W1, b1, W2, b2, W3, b3, W4, b4,
                                             Wo, bo, C1, C2, C3, out, n);
}